// Round 1
// baseline (98784.161 us; speedup 1.0000x reference)
//
#include <hip/hip_runtime.h>
#include <math.h>

// Problem constants
#define BB 256      // batch
#define TT 250      // timesteps
#define NS 500      // stocks (input dim / output dim)
#define HH 512      // hidden
#define G3 1536     // 3*HH
#define NBLK 512    // total blocks: 2 layers x 16 batch-groups x 16 unit-groups
#define TBLK 256    // threads per block

__device__ __forceinline__ float sigm(float x) { return 1.f / (1.f + expf(-x)); }

// ---------------- grid barrier (monotonic counter, sense via phase) ----------------
__device__ __forceinline__ void gbar(unsigned* cnt, unsigned* flag, unsigned phase) {
    __threadfence();          // release this thread's global stores (agent scope)
    __syncthreads();          // all threads of block fenced before arrival
    if (threadIdx.x == 0) {
        unsigned arrived = __hip_atomic_fetch_add(cnt, 1u, __ATOMIC_ACQ_REL,
                                                  __HIP_MEMORY_SCOPE_AGENT) + 1u;
        if (arrived == (unsigned)NBLK * phase) {
            __hip_atomic_store(flag, phase, __ATOMIC_RELEASE, __HIP_MEMORY_SCOPE_AGENT);
        } else {
            while (__hip_atomic_load(flag, __ATOMIC_ACQUIRE, __HIP_MEMORY_SCOPE_AGENT) < phase) {
                __builtin_amdgcn_s_sleep(2);
            }
        }
    }
    __syncthreads();
}

// ---------------- one GRU step for a (16-batch x 32-unit) tile ----------------
// WT: (KX+512) x 1536, k-major (rows 0..KX-1 = W_ih^T, rows KX.. = W_hh^T)
// src_x: 16 rows x KX (row stride sx), src_h: 16 rows x 512 (stride 512)
// hout: 16 rows x 512 (stride 512), pre-offset to this block's batch group
template <int KX>
__device__ __forceinline__ void gru_step(
    const float* __restrict__ WT,
    const float* __restrict__ b_i, const float* __restrict__ b_h,
    const float* __restrict__ src_x, size_t sx,
    const float* __restrict__ src_h,
    float* __restrict__ hout,
    int U0, float* smem)
{
    const int tid = threadIdx.x;
    float* a0 = smem;            // 16 x KX
    float* a1 = smem + 16 * KX;  // 16 x 512
    {
        const int nf4 = KX / 4;  // KX is 500 or 512, both %4==0
        for (int i = tid; i < 16 * nf4; i += TBLK) {
            int r = i / nf4, c = i - r * nf4;
            float4 v = ((const float4*)(src_x + (size_t)r * sx))[c];
            ((float4*)(a0 + r * KX))[c] = v;
        }
    }
    for (int i = tid; i < 16 * 128; i += TBLK) {
        int r = i >> 7, c = i & 127;
        float4 v = ((const float4*)(src_h + (size_t)r * 512))[c];
        ((float4*)(a1 + (size_t)r * 512))[c] = v;
    }
    __syncthreads();

    const int ul = tid & 15;     // 16 unit-lanes, 2 units each
    const int bl = tid >> 4;     // 16 batches
    const int c0 = U0 + 2 * ul;  // global gate/unit column (0..510)

    float2 giR = *(const float2*)(b_i + c0);
    float2 giZ = *(const float2*)(b_i + 512 + c0);
    float2 giN = *(const float2*)(b_i + 1024 + c0);
    float2 ghR = *(const float2*)(b_h + c0);
    float2 ghZ = *(const float2*)(b_h + 512 + c0);
    float2 ghN = *(const float2*)(b_h + 1024 + c0);

    const float* arow = a0 + bl * KX;
    const float* WTc = WT + c0;
#pragma unroll 4
    for (int k = 0; k < KX; ++k) {
        float a = arow[k];
        const float* wr = WTc + (size_t)k * G3;
        float2 wR = *(const float2*)(wr);
        float2 wZ = *(const float2*)(wr + 512);
        float2 wN = *(const float2*)(wr + 1024);
        giR.x = fmaf(a, wR.x, giR.x); giR.y = fmaf(a, wR.y, giR.y);
        giZ.x = fmaf(a, wZ.x, giZ.x); giZ.y = fmaf(a, wZ.y, giZ.y);
        giN.x = fmaf(a, wN.x, giN.x); giN.y = fmaf(a, wN.y, giN.y);
    }
    const float* hrow = a1 + (size_t)bl * 512;
    const float* WTh = WTc + (size_t)KX * G3;
#pragma unroll 4
    for (int k = 0; k < 512; ++k) {
        float a = hrow[k];
        const float* wr = WTh + (size_t)k * G3;
        float2 wR = *(const float2*)(wr);
        float2 wZ = *(const float2*)(wr + 512);
        float2 wN = *(const float2*)(wr + 1024);
        ghR.x = fmaf(a, wR.x, ghR.x); ghR.y = fmaf(a, wR.y, ghR.y);
        ghZ.x = fmaf(a, wZ.x, ghZ.x); ghZ.y = fmaf(a, wZ.y, ghZ.y);
        ghN.x = fmaf(a, wN.x, ghN.x); ghN.y = fmaf(a, wN.y, ghN.y);
    }

    float2 hp = *(const float2*)(hrow + c0);
    float rx = sigm(giR.x + ghR.x), ry = sigm(giR.y + ghR.y);
    float zx = sigm(giZ.x + ghZ.x), zy = sigm(giZ.y + ghZ.y);
    float nx = tanhf(giN.x + rx * ghN.x), ny = tanhf(giN.y + ry * ghN.y);
    float2 hn;
    hn.x = (1.f - zx) * nx + zx * hp.x;
    hn.y = (1.f - zy) * ny + zy * hp.y;
    *(float2*)(hout + (size_t)bl * 512 + c0) = hn;
    // no trailing syncthreads: the grid barrier right after provides it
}

// ---------------- block reductions (256 threads = 4 waves of 64) ----------------
__device__ __forceinline__ float block_reduce_max(float v, float* scr) {
#pragma unroll
    for (int off = 32; off; off >>= 1) v = fmaxf(v, __shfl_down(v, off, 64));
    if ((threadIdx.x & 63) == 0) scr[threadIdx.x >> 6] = v;
    __syncthreads();
    if (threadIdx.x == 0) scr[8] = fmaxf(fmaxf(scr[0], scr[1]), fmaxf(scr[2], scr[3]));
    __syncthreads();
    float r = scr[8];
    __syncthreads();
    return r;
}

__device__ __forceinline__ float2 block_reduce_sum2(float a, float b, float* scr) {
#pragma unroll
    for (int off = 32; off; off >>= 1) {
        a += __shfl_down(a, off, 64);
        b += __shfl_down(b, off, 64);
    }
    if ((threadIdx.x & 63) == 0) {
        int wid = threadIdx.x >> 6;
        scr[wid] = a; scr[4 + wid] = b;
    }
    __syncthreads();
    if (threadIdx.x == 0) {
        scr[8] = scr[0] + scr[1] + scr[2] + scr[3];
        scr[9] = scr[4] + scr[5] + scr[6] + scr[7];
    }
    __syncthreads();
    float2 r = make_float2(scr[8], scr[9]);
    __syncthreads();
    return r;
}

// ---------------- main persistent kernel ----------------
__global__ void __launch_bounds__(TBLK)
gru_main(const float* __restrict__ x,
         const float* __restrict__ bi0, const float* __restrict__ bh0,
         const float* __restrict__ bi1, const float* __restrict__ bh1,
         const float* __restrict__ fcb,
         const float* __restrict__ WT0, const float* __restrict__ WT1,
         const float* __restrict__ fcT,
         float* hA, float* hB, unsigned* cnt, unsigned* flag,
         float* __restrict__ out)
{
    extern __shared__ float smem[];
    const int bid = blockIdx.x, tid = threadIdx.x;
    const int lay = bid >> 8;       // 0: layer0 blocks 0..255, 1: layer1 blocks 256..511
    const int lb = bid & 255;
    const int b0 = (lb >> 4) * 16;  // batch group base
    const int U0 = (lb & 15) * 32;  // unit group base

    unsigned phase = 0;
    for (int s = 0; s <= TT; ++s) {
        const int par = s & 1;
        if (lay == 0) {
            if (s < TT) {
                // layer 0, t = s: reads x[:,t,:] and hA[par], writes hA[1-par]
                gru_step<NS>(WT0, bi0, bh0,
                             x + ((size_t)b0 * TT + s) * NS, (size_t)TT * NS,
                             hA + (size_t)par * (BB * HH) + (size_t)b0 * HH,
                             hA + (size_t)(1 - par) * (BB * HH) + (size_t)b0 * HH,
                             U0, smem);
            }
        } else {
            if (s >= 1) {
                // layer 1, t1 = s-1: reads hA[par] (=h_l0[t1]) and hB[1-par], writes hB[par]
                gru_step<HH>(WT1, bi1, bh1,
                             hA + (size_t)par * (BB * HH) + (size_t)b0 * HH, (size_t)HH,
                             hB + (size_t)(1 - par) * (BB * HH) + (size_t)b0 * HH,
                             hB + (size_t)par * (BB * HH) + (size_t)b0 * HH,
                             U0, smem);
            }
        }
        ++phase;
        gbar(cnt, flag, phase);
    }

    // ---------------- FC + silu + softmax + rebalance: one block per batch row ----------------
    if (bid < BB) {
        const float* hrow = hB + (size_t)bid * HH;  // final h_l1 lives in hB[0] (t=249 -> par 0)
        float* sh = smem;          // 512 floats
        float* scr = smem + 768;   // reduction scratch
        for (int i = tid; i < HH / 4; i += TBLK)
            ((float4*)sh)[i] = ((const float4*)hrow)[i];
        __syncthreads();

        const int o1 = tid;                   // 0..255, always < 500
        const bool v2 = (tid + 256) < NS;     // second output valid for tid < 244
        const int o2 = v2 ? (tid + 256) : (NS - 1);

        float a0 = fcb[o1], a1 = fcb[o2];
        for (int k = 0; k < HH; ++k) {
            float hv = sh[k];
            const float* fr = fcT + (size_t)k * NS;
            a0 = fmaf(hv, fr[o1], a0);
            a1 = fmaf(hv, fr[o2], a1);
        }
        // silu
        float l0 = a0 * sigm(a0);
        float l1 = a1 * sigm(a1);
        // softmax over 500
        float mx = block_reduce_max(fmaxf(l0, v2 ? l1 : -3.4e38f), scr);
        float e0 = expf(l0 - mx);
        float e1 = v2 ? expf(l1 - mx) : 0.f;
        float2 s2 = block_reduce_sum2(e0 + e1, 0.f, scr);
        float w0 = e0 / s2.x;
        float w1 = e1 / s2.x;
        // 30 rebalance iterations
        for (int it = 0; it < 30; ++it) {
            float c0v = fminf(fmaxf(w0, 0.f), 0.1f);
            float c1v = fminf(fmaxf(w1, 0.f), 0.1f);
            float lv = (w0 - c0v) + (w1 - c1v);
            float n0 = (c0v != 0.1f) ? c0v : 0.f;
            float n1 = (v2 && c1v != 0.1f) ? c1v : 0.f;
            float2 rs = block_reduce_sum2(lv, n0 + n1, scr);
            float inv = rs.x / rs.y;
            w0 = c0v + inv * n0;
            w1 = c1v + inv * n1;
        }
        out[(size_t)bid * NS + o1] = w0;
        if (v2) out[(size_t)bid * NS + tid + 256] = w1;
    }
}

// ---------------- weight transpose prep: dst[k*G + g] = src[g*K + k] ----------------
__global__ void transpose_k(const float* __restrict__ src, float* __restrict__ dst,
                            int G, int K) {
    int idx = blockIdx.x * 256 + threadIdx.x;
    if (idx >= G * K) return;
    int k = idx / G, g = idx - k * G;
    dst[idx] = src[(size_t)g * K + k];
}

// ---------------- launch ----------------
extern "C" void kernel_launch(void* const* d_in, const int* in_sizes, int n_in,
                              void* d_out, int out_size, void* d_ws, size_t ws_size,
                              hipStream_t stream) {
    const float* x    = (const float*)d_in[0];
    const float* wih0 = (const float*)d_in[1];
    const float* whh0 = (const float*)d_in[2];
    const float* bih0 = (const float*)d_in[3];
    const float* bhh0 = (const float*)d_in[4];
    const float* wih1 = (const float*)d_in[5];
    const float* whh1 = (const float*)d_in[6];
    const float* bih1 = (const float*)d_in[7];
    const float* bhh1 = (const float*)d_in[8];
    const float* fcw  = (const float*)d_in[9];
    const float* fcb  = (const float*)d_in[10];
    float* outp = (float*)d_out;

    char* ws = (char*)d_ws;
    unsigned* cnt  = (unsigned*)ws;          // monotonic arrival counter
    unsigned* flag = (unsigned*)(ws + 128);  // phase flag (separate cache line)
    float* hA  = (float*)(ws + 256);         // 2 x 256 x 512
    float* hB  = hA + 2 * BB * HH;           // 2 x 256 x 512
    float* WT0 = hB + 2 * BB * HH;           // 1012 x 1536
    float* WT1 = WT0 + (size_t)(NS + HH) * G3;   // 1024 x 1536
    float* fcT = WT1 + (size_t)(2 * HH) * G3;    // 512 x 500

    // zero barrier state + h buffers (h0 = 0)
    hipMemsetAsync(ws, 0, 256 + (size_t)2 * 2 * BB * HH * sizeof(float), stream);

    // k-major transposed weights (coalesced inner-loop loads in gru_main)
    {
        int n;
        n = G3 * NS;  transpose_k<<<(n + 255) / 256, 256, 0, stream>>>(wih0, WT0, G3, NS);
        n = G3 * HH;  transpose_k<<<(n + 255) / 256, 256, 0, stream>>>(whh0, WT0 + (size_t)NS * G3, G3, HH);
        n = G3 * HH;  transpose_k<<<(n + 255) / 256, 256, 0, stream>>>(wih1, WT1, G3, HH);
        n = G3 * HH;  transpose_k<<<(n + 255) / 256, 256, 0, stream>>>(whh1, WT1 + (size_t)HH * G3, G3, HH);
        n = NS * HH;  transpose_k<<<(n + 255) / 256, 256, 0, stream>>>(fcw, fcT, NS, HH);
    }

    void* args[] = {(void*)&x, (void*)&bih0, (void*)&bhh0, (void*)&bih1, (void*)&bhh1,
                    (void*)&fcb, (void*)&WT0, (void*)&WT1, (void*)&fcT,
                    (void*)&hA, (void*)&hB, (void*)&cnt, (void*)&flag, (void*)&outp};
    hipError_t e = hipLaunchCooperativeKernel((const void*)gru_main, dim3(NBLK), dim3(TBLK),
                                              args, 65536, stream);
    if (e != hipSuccess) {
        // fallback: plain launch (512 blocks x (64KB LDS, 256 thr) = exactly 2/CU, co-resident)
        gru_main<<<dim3(NBLK), dim3(TBLK), 65536, stream>>>(
            x, bih0, bhh0, bih1, bhh1, fcb, WT0, WT1, fcT, hA, hB, cnt, flag, outp);
    }
}

// Round 2
// 34305.261 us; speedup vs baseline: 2.8796x; 2.8796x over previous
//
#include <hip/hip_runtime.h>
#include <math.h>

// Problem constants
#define BB 256      // batch
#define TT 250      // timesteps
#define NS 500      // stocks (input dim / output dim)
#define HH 512      // hidden
#define TNS (TT * NS)
#define HS (HH * BB)       // one h buffer (transposed [unit][batch]) in floats
#define XSL (NS * BB)      // one xT slice in floats
#define NBLK 256    // 2 layers x 128 unit-groups
#define TBLK 512    // 8 waves: 4 unit-waves x 2 K-halves
// LDS: weights [k][u][g] up to 1024*12 floats, then gi scratch 12*256 floats
#define WMAXF (1024 * 12)
#define GIOFF WMAXF
#define SMEMB ((WMAXF + 12 * 256) * 4)   // 61440 bytes

__device__ __forceinline__ float sigm(float x) { return 1.f / (1.f + expf(-x)); }

// ---------------- grid barrier (monotonic counter + phase flag) ----------------
__device__ __forceinline__ void gbar(unsigned* cnt, unsigned* flag, unsigned phase) {
    __threadfence();
    __syncthreads();
    if (threadIdx.x == 0) {
        unsigned arrived = __hip_atomic_fetch_add(cnt, 1u, __ATOMIC_ACQ_REL,
                                                  __HIP_MEMORY_SCOPE_AGENT) + 1u;
        if (arrived == (unsigned)NBLK * phase) {
            __hip_atomic_store(flag, phase, __ATOMIC_RELEASE, __HIP_MEMORY_SCOPE_AGENT);
        } else {
            while (__hip_atomic_load(flag, __ATOMIC_ACQUIRE, __HIP_MEMORY_SCOPE_AGENT) < phase) {
                __builtin_amdgcn_s_sleep(2);
            }
        }
    }
    __syncthreads();
}

// ---------------- one half-GEMM: acc[3 gates][4 batches] over K, weights in LDS ----
// asrc: activation matrix [K][256] (transposed layout), lane covers batches b4..b4+3
// wbase: LDS weights, this wave's unit => wbase + ul*3, stride 12 per k
template <int KK>
__device__ __forceinline__ void half_gemm(const float* __restrict__ asrc, int b4,
                                          const float* __restrict__ wbase, int ul,
                                          float4& aR, float4& aZ, float4& aN) {
    const float* wp = wbase + ul * 3;
    const float* ap = asrc + b4;
#pragma unroll 8
    for (int k = 0; k < KK; ++k) {
        float4 hv = *(const float4*)(ap);
        ap += BB;
        float wr = wp[0], wz = wp[1], wn = wp[2];
        wp += 12;
        aR.x = fmaf(wr, hv.x, aR.x); aR.y = fmaf(wr, hv.y, aR.y);
        aR.z = fmaf(wr, hv.z, aR.z); aR.w = fmaf(wr, hv.w, aR.w);
        aZ.x = fmaf(wz, hv.x, aZ.x); aZ.y = fmaf(wz, hv.y, aZ.y);
        aZ.z = fmaf(wz, hv.z, aZ.z); aZ.w = fmaf(wz, hv.w, aZ.w);
        aN.x = fmaf(wn, hv.x, aN.x); aN.y = fmaf(wn, hv.y, aN.y);
        aN.z = fmaf(wn, hv.z, aN.z); aN.w = fmaf(wn, hv.w, aN.w);
    }
}

// ---------------- block reductions (512 threads = 8 waves) ----------------
__device__ __forceinline__ float block_max8(float v, float* scr) {
#pragma unroll
    for (int off = 32; off; off >>= 1) v = fmaxf(v, __shfl_down(v, off, 64));
    if ((threadIdx.x & 63) == 0) scr[threadIdx.x >> 6] = v;
    __syncthreads();
    if (threadIdx.x == 0) {
        float m = scr[0];
#pragma unroll
        for (int i = 1; i < 8; ++i) m = fmaxf(m, scr[i]);
        scr[16] = m;
    }
    __syncthreads();
    float r = scr[16];
    __syncthreads();
    return r;
}

__device__ __forceinline__ float2 block_sum2_8(float a, float b, float* scr) {
#pragma unroll
    for (int off = 32; off; off >>= 1) {
        a += __shfl_down(a, off, 64);
        b += __shfl_down(b, off, 64);
    }
    if ((threadIdx.x & 63) == 0) {
        int wid = threadIdx.x >> 6;
        scr[wid] = a; scr[8 + wid] = b;
    }
    __syncthreads();
    if (threadIdx.x == 0) {
        float sa = 0.f, sb = 0.f;
#pragma unroll
        for (int i = 0; i < 8; ++i) { sa += scr[i]; sb += scr[8 + i]; }
        scr[16] = sa; scr[17] = sb;
    }
    __syncthreads();
    float2 r = make_float2(scr[16], scr[17]);
    __syncthreads();
    return r;
}

// ---------------- main persistent kernel ----------------
__global__ void __launch_bounds__(TBLK)
gru_main(const float* __restrict__ x,
         const float* __restrict__ wih0, const float* __restrict__ whh0,
         const float* __restrict__ bi0,  const float* __restrict__ bh0,
         const float* __restrict__ wih1, const float* __restrict__ whh1,
         const float* __restrict__ bi1,  const float* __restrict__ bh1,
         const float* __restrict__ fcb,  const float* __restrict__ fcT,
         float* hA, float* hB, float* xT,
         unsigned* cnt, unsigned* flag,
         float* __restrict__ out)
{
    extern __shared__ float smem[];
    float* wsm = smem;
    float* gsm = smem + GIOFF;

    const int bid = blockIdx.x, tid = threadIdx.x;
    const int lay = bid >> 7;          // 0 or 1
    const int ug  = bid & 127;
    const int U0  = ug * 4;
    const int wid  = tid >> 6, lane = tid & 63;
    const int ul   = wid & 3;          // unit within group (one per wave)
    const int half = wid >> 2;         // 0 = input projection (gi), 1 = recurrent (gh)
    const int ugl  = U0 + ul;          // global unit index
    const int b4   = lane * 4;         // 4 batches per lane
    const int KXin = lay ? HH : NS;    // input-projection K

    // ---- stage this block's weight slice into LDS (once): wsm[k*12 + u*3 + g] ----
    {
        const float* wih = lay ? wih1 : wih0;
        const float* whh = lay ? whh1 : whh0;
        const int ktot = KXin + HH;
        for (int i = tid; i < ktot * 12; i += TBLK) {
            int k = i / 12, r = i - k * 12;
            int u = r / 3, g = r - 3 * u;
            int row = g * HH + U0 + u;
            wsm[i] = (k < KXin) ? wih[(size_t)row * KXin + k]
                                : whh[(size_t)row * HH + (k - KXin)];
        }
    }
    // per-wave biases
    const float* bsel = half ? (lay ? bh1 : bh0) : (lay ? bi1 : bi0);
    const float biasR = bsel[ugl], biasZ = bsel[HH + ugl], biasN = bsel[2 * HH + ugl];
    __syncthreads();

    // ---- time loop: phases s=-1..250 (252 grid barriers) ----
    unsigned phase = 0;
    for (int s = -1; s <= TT; ++s) {
        const int par = s & 1;
        const bool active = lay ? (s >= 1) : (s >= 0 && s < TT);
        if (active) {
            const float* asrc; const float* wbase;
            const float* hprev; float* hout;
            if (lay == 0) {
                hprev = hA + (size_t)par * HS;
                hout  = hA + (size_t)(1 - par) * HS;
                if (half == 0) { asrc = xT + (size_t)(s & 1) * XSL; wbase = wsm; }
                else           { asrc = hprev; wbase = wsm + NS * 12; }
            } else {
                hprev = hB + (size_t)(1 - par) * HS;
                hout  = hB + (size_t)par * HS;
                if (half == 0) { asrc = hA + (size_t)par * HS; wbase = wsm; }
                else           { asrc = hprev; wbase = wsm + HH * 12; }
            }
            float4 aR = make_float4(biasR, biasR, biasR, biasR);
            float4 aZ = make_float4(biasZ, biasZ, biasZ, biasZ);
            float4 aN = make_float4(biasN, biasN, biasN, biasN);
            if (half == 0 && lay == 0) half_gemm<NS>(asrc, b4, wbase, ul, aR, aZ, aN);
            else                       half_gemm<HH>(asrc, b4, wbase, ul, aR, aZ, aN);

            float* g0 = gsm + ul * (3 * BB) + b4;
            if (half == 0) {
                *(float4*)(g0)          = aR;
                *(float4*)(g0 + BB)     = aZ;
                *(float4*)(g0 + 2 * BB) = aN;
            }
            __syncthreads();
            if (half == 1) {
                float4 giR = *(const float4*)(g0);
                float4 giZ = *(const float4*)(g0 + BB);
                float4 giN = *(const float4*)(g0 + 2 * BB);
                float4 hp  = *(const float4*)(hprev + (size_t)ugl * BB + b4);
                float4 hn;
                {
                    float r = sigm(giR.x + aR.x), z = sigm(giZ.x + aZ.x);
                    float n = tanhf(giN.x + r * aN.x);
                    hn.x = (1.f - z) * n + z * hp.x;
                }
                {
                    float r = sigm(giR.y + aR.y), z = sigm(giZ.y + aZ.y);
                    float n = tanhf(giN.y + r * aN.y);
                    hn.y = (1.f - z) * n + z * hp.y;
                }
                {
                    float r = sigm(giR.z + aR.z), z = sigm(giZ.z + aZ.z);
                    float n = tanhf(giN.z + r * aN.z);
                    hn.z = (1.f - z) * n + z * hp.z;
                }
                {
                    float r = sigm(giR.w + aR.w), z = sigm(giZ.w + aZ.w);
                    float n = tanhf(giN.w + r * aN.w);
                    hn.w = (1.f - z) * n + z * hp.w;
                }
                *(float4*)(hout + (size_t)ugl * BB + b4) = hn;
            }
        }
        // layer-0 blocks also transpose the NEXT x slice: xT[(s+1)&1][k][b] = x[b][s+1][k]
        if (lay == 0 && (s + 1) < TT) {
            int idx = ug * TBLK + tid;                 // 0..65535; need 500*64=32000
            if (idx < NS * 64) {
                int k = idx >> 6, bb = (idx & 63) * 4;
                const float* xb = x + (size_t)(s + 1) * NS + k;
                float4 v;
                v.x = xb[(size_t)(bb + 0) * TNS];
                v.y = xb[(size_t)(bb + 1) * TNS];
                v.z = xb[(size_t)(bb + 2) * TNS];
                v.w = xb[(size_t)(bb + 3) * TNS];
                *(float4*)(xT + (size_t)((s + 1) & 1) * XSL + (size_t)k * BB + bb) = v;
            }
        }
        ++phase;
        gbar(cnt, flag, phase);
    }

    // ---------------- epilogue: FC + silu + softmax + rebalance (1 block per batch) ----
    {
        const int b = bid;                 // 256 blocks = 256 batches
        float* sh  = smem;                 // 512 floats: h for this batch
        float* scr = smem + 640;           // reduction scratch (>= 18 floats)
        for (int k = tid; k < HH; k += TBLK) sh[k] = hB[(size_t)k * BB + b];
        __syncthreads();

        const bool act = tid < NS;
        const int o = act ? tid : (NS - 1);
        float a = fcb[o];
        for (int k = 0; k < HH; ++k) a = fmaf(sh[k], fcT[(size_t)k * NS + o], a);
        float l = a * sigm(a);             // silu
        float mx = block_max8(act ? l : -3.4e38f, scr);
        float e = act ? expf(l - mx) : 0.f;
        float2 s2 = block_sum2_8(e, 0.f, scr);
        float w = e / s2.x;
        for (int it = 0; it < 30; ++it) {
            float wc = fminf(fmaxf(w, 0.f), 0.1f);
            float lv = w - wc;
            float nom = (wc != 0.1f) ? wc : 0.f;
            float2 rs = block_sum2_8(lv, nom, scr);
            w = wc + rs.x * nom / rs.y;
        }
        if (act) out[(size_t)b * NS + tid] = w;
    }
}

// ---------------- fc weight transpose: fcT[k*NS + o] = fcw[o*HH + k] ----------------
__global__ void transpose_k(const float* __restrict__ src, float* __restrict__ dst,
                            int G, int K) {
    int idx = blockIdx.x * 256 + threadIdx.x;
    if (idx >= G * K) return;
    int k = idx / G, g = idx - k * G;
    dst[idx] = src[(size_t)g * K + k];
}

// ---------------- launch ----------------
extern "C" void kernel_launch(void* const* d_in, const int* in_sizes, int n_in,
                              void* d_out, int out_size, void* d_ws, size_t ws_size,
                              hipStream_t stream) {
    const float* x    = (const float*)d_in[0];
    const float* wih0 = (const float*)d_in[1];
    const float* whh0 = (const float*)d_in[2];
    const float* bih0 = (const float*)d_in[3];
    const float* bhh0 = (const float*)d_in[4];
    const float* wih1 = (const float*)d_in[5];
    const float* whh1 = (const float*)d_in[6];
    const float* bih1 = (const float*)d_in[7];
    const float* bhh1 = (const float*)d_in[8];
    const float* fcw  = (const float*)d_in[9];
    const float* fcb  = (const float*)d_in[10];
    float* outp = (float*)d_out;

    char* ws = (char*)d_ws;
    unsigned* cnt  = (unsigned*)ws;
    unsigned* flag = (unsigned*)(ws + 128);
    float* hA  = (float*)(ws + 256);          // 2 x (512x256) transposed h, layer 0
    float* hB  = hA + 2 * HS;                 // 2 x (512x256) transposed h, layer 1
    float* xT  = hB + 2 * HS;                 // 2 x (500x256) transposed x slices
    float* fcT = xT + 2 * XSL;                // 512 x 500

    // zero barrier state + h buffers (h0 = 0)
    hipMemsetAsync(ws, 0, 256 + (size_t)4 * HS * sizeof(float), stream);
    {
        int n = NS * HH;
        transpose_k<<<(n + 255) / 256, 256, 0, stream>>>(fcw, fcT, NS, HH);
    }

    void* args[] = {(void*)&x,
                    (void*)&wih0, (void*)&whh0, (void*)&bih0, (void*)&bhh0,
                    (void*)&wih1, (void*)&whh1, (void*)&bih1, (void*)&bhh1,
                    (void*)&fcb, (void*)&fcT,
                    (void*)&hA, (void*)&hB, (void*)&xT,
                    (void*)&cnt, (void*)&flag, (void*)&outp};
    hipError_t e = hipLaunchCooperativeKernel((const void*)gru_main, dim3(NBLK), dim3(TBLK),
                                              args, SMEMB, stream);
    if (e != hipSuccess) {
        gru_main<<<dim3(NBLK), dim3(TBLK), SMEMB, stream>>>(
            x, wih0, whh0, bih0, bhh0, wih1, whh1, bih1, bhh1,
            fcb, fcT, hA, hB, xT, cnt, flag, outp);
    }
}

// Round 4
// 33961.038 us; speedup vs baseline: 2.9087x; 1.0101x over previous
//
#include <hip/hip_runtime.h>
#include <math.h>

typedef __attribute__((ext_vector_type(8))) short short8;
typedef __attribute__((ext_vector_type(4))) float floatx4;
typedef unsigned short ushort_t;
typedef unsigned int uint32;

#define BB 256
#define TT 250
#define NS 500
#define HH 512
#define NBLK 256
#define TBLK 256
#define PL_USH 131072u      // act plane: 16ch*16ct*64lane*8 ushorts (512K x 256 bf16)
#define CH_USH 8192u        // act chunk stride: 16ct*64*8
#define WSLICE_USH 24576u   // W-lo slice: 16ch*3s3*512 ushorts (48 rows x 512 k)

// ---- bf16 split helpers (RNE) ----
__device__ __forceinline__ ushort_t f2bf(float f) {
    uint32 u = __float_as_uint(f);
    u += 0x7fffu + ((u >> 16) & 1u);
    return (ushort_t)(u >> 16);
}
__device__ __forceinline__ float bf2f(ushort_t h) { return __uint_as_float(((uint32)h) << 16); }
__device__ __forceinline__ float sigm(float x) { return 1.f / (1.f + expf(-x)); }
__device__ __forceinline__ floatx4 mfma16(short8 a, short8 b, floatx4 c) {
    return __builtin_amdgcn_mfma_f32_16x16x32_bf16(a, b, c, 0, 0, 0);
}

// ---------------- two-level grid barrier (8 groups x 32 blocks) ----------------
__device__ __forceinline__ void gbar(unsigned* bar, unsigned phase, int grp) {
    __threadfence();
    __syncthreads();
    if (threadIdx.x == 0) {
        unsigned* sub   = bar + (grp << 4);   // 64B apart
        unsigned* mcnt  = bar + 128;          // +512B
        unsigned* mflag = bar + 256;          // +1024B
        unsigned a = __hip_atomic_fetch_add(sub, 1u, __ATOMIC_ACQ_REL,
                                            __HIP_MEMORY_SCOPE_AGENT) + 1u;
        if (a == 32u * phase) {
            unsigned m = __hip_atomic_fetch_add(mcnt, 1u, __ATOMIC_ACQ_REL,
                                                __HIP_MEMORY_SCOPE_AGENT) + 1u;
            if (m == 8u * phase)
                __hip_atomic_store(mflag, phase, __ATOMIC_RELEASE, __HIP_MEMORY_SCOPE_AGENT);
        }
        while (__hip_atomic_load(mflag, __ATOMIC_ACQUIRE, __HIP_MEMORY_SCOPE_AGENT) < phase) {
            __builtin_amdgcn_s_sleep(2);
        }
    }
    __syncthreads();
}

// ---------------- block reductions (256 thr = 4 waves) ----------------
__device__ __forceinline__ float block_max4(float v, float* scr) {
#pragma unroll
    for (int off = 32; off; off >>= 1) v = fmaxf(v, __shfl_down(v, off, 64));
    if ((threadIdx.x & 63) == 0) scr[threadIdx.x >> 6] = v;
    __syncthreads();
    if (threadIdx.x == 0)
        scr[8] = fmaxf(fmaxf(scr[0], scr[1]), fmaxf(scr[2], scr[3]));
    __syncthreads();
    float r = scr[8];
    __syncthreads();
    return r;
}
__device__ __forceinline__ float2 block_sum2_4(float a, float b, float* scr) {
#pragma unroll
    for (int off = 32; off; off >>= 1) {
        a += __shfl_down(a, off, 64);
        b += __shfl_down(b, off, 64);
    }
    if ((threadIdx.x & 63) == 0) { int w = threadIdx.x >> 6; scr[w] = a; scr[4 + w] = b; }
    __syncthreads();
    if (threadIdx.x == 0) {
        scr[8] = scr[0] + scr[1] + scr[2] + scr[3];
        scr[9] = scr[4] + scr[5] + scr[6] + scr[7];
    }
    __syncthreads();
    float2 r = make_float2(scr[8], scr[9]);
    __syncthreads();
    return r;
}

// ---------------- main persistent kernel ----------------
__global__ void __launch_bounds__(TBLK)
gru_main(const float* __restrict__ x,
         const float* __restrict__ wih0, const float* __restrict__ whh0,
         const float* __restrict__ bi0,  const float* __restrict__ bh0,
         const float* __restrict__ wih1, const float* __restrict__ whh1,
         const float* __restrict__ bi1,  const float* __restrict__ bh1,
         const float* __restrict__ fcw,  const float* __restrict__ fcb,
         const ushort_t* __restrict__ WloP,
         ushort_t* xpack, ushort_t* h0pack, ushort_t* h1pack,
         float* gbuf, unsigned* bar,
         float* __restrict__ out)
{
    extern __shared__ char smem_raw[];
    ushort_t* wlds = (ushort_t*)smem_raw;    // 48 rows x 512 k hi-plane frags (49152 B)

    const int bid = blockIdx.x, tid = threadIdx.x;
    const int L   = bid >> 7;
    const int HF  = (bid >> 6) & 1;          // 0=gi (input side), 1=gh (recurrent side)
    const int RT  = (bid & 63) >> 1;         // 32 row tiles of 48 rows
    const int CT2 = bid & 1;                 // col half (128 cols)
    const int wid = tid >> 6, lane = tid & 63;
    const int q = lane >> 4, n = lane & 15;

    // ---- stage W-hi into LDS directly from fp32 source (A-frag layout) ----
    {
        const float* Wsrc = L ? (HF ? whh1 : wih1) : (HF ? whh0 : wih0);
        const int K = (L == 0 && HF == 0) ? NS : HH;
        for (int idx = tid; idx < 48 * 512; idx += TBLK) {
            const int rl = idx >> 9, k = idx & 511;
            const int s3 = rl >> 4, m = rl & 15;
            float v = (k < K) ? Wsrc[(size_t)(RT * 48 + s3 * 16 + m) * K + k] : 0.f;
            wlds[((size_t)(k >> 5) * 3 + s3) * 512 + (((k >> 3) & 3) * 16 + m) * 8 + (k & 7)] = f2bf(v);
        }
    }
    __syncthreads();

    float hreg[8];
#pragma unroll
    for (int j = 0; j < 8; ++j) hreg[j] = 0.f;

    const int gt = bid * TBLK + tid;
    const int grp = bid & 7;
    const ushort_t* wloS = WloP + (size_t)((L * 2 + HF) * 32 + RT) * WSLICE_USH + (size_t)lane * 8;
    const ushort_t* whiS = wlds + (size_t)lane * 8;
    const int ct0 = CT2 * 8 + wid * 2;

    unsigned phase = 0;
    for (int s = 0; s <= TT; ++s) {
        // ================= PHASE A: GEMM (split-bf16, 3-term) =================
        const bool activeA = L ? (s >= 1) : (s <= TT - 1);
        if (activeA) {
            const ushort_t* actsrc;
            if (L == 0)
                actsrc = HF ? h0pack + (size_t)((s - 1) & 1) * 2 * PL_USH
                            : xpack + (size_t)(s & 1) * 2 * PL_USH;
            else
                actsrc = HF ? h1pack + (size_t)(s & 1) * 2 * PL_USH
                            : h0pack + (size_t)((s - 1) & 1) * 2 * PL_USH;
            const ushort_t* ap = actsrc + ((size_t)ct0 * 64 + lane) * 8;

            floatx4 z4 = {0.f, 0.f, 0.f, 0.f};
            floatx4 acc[3][2];
#pragma unroll
            for (int i = 0; i < 3; ++i) { acc[i][0] = z4; acc[i][1] = z4; }

            short8 bh0v = *(const short8*)(ap);
            short8 bh1v = *(const short8*)(ap + 512);
            short8 bl0v = *(const short8*)(ap + PL_USH);
            short8 bl1v = *(const short8*)(ap + PL_USH + 512);
            short8 wl0 = *(const short8*)(wloS);
            short8 wl1 = *(const short8*)(wloS + 512);
            short8 wl2 = *(const short8*)(wloS + 1024);

            for (int c = 0; c < 16; ++c) {
                short8 nbh0, nbh1, nbl0, nbl1, nwl0, nwl1, nwl2;
                if (c < 15) {
                    const ushort_t* p = ap + (size_t)(c + 1) * CH_USH;
                    nbh0 = *(const short8*)(p);
                    nbh1 = *(const short8*)(p + 512);
                    nbl0 = *(const short8*)(p + PL_USH);
                    nbl1 = *(const short8*)(p + PL_USH + 512);
                    const ushort_t* wp = wloS + (size_t)(c + 1) * 1536;
                    nwl0 = *(const short8*)(wp);
                    nwl1 = *(const short8*)(wp + 512);
                    nwl2 = *(const short8*)(wp + 1024);
                }
                const ushort_t* wh = whiS + (size_t)c * 1536;
                short8 wh0 = *(const short8*)(wh);
                short8 wh1 = *(const short8*)(wh + 512);
                short8 wh2 = *(const short8*)(wh + 1024);

                acc[0][0] = mfma16(wh0, bh0v, acc[0][0]);
                acc[0][0] = mfma16(wh0, bl0v, acc[0][0]);
                acc[0][0] = mfma16(wl0, bh0v, acc[0][0]);
                acc[0][1] = mfma16(wh0, bh1v, acc[0][1]);
                acc[0][1] = mfma16(wh0, bl1v, acc[0][1]);
                acc[0][1] = mfma16(wl0, bh1v, acc[0][1]);
                acc[1][0] = mfma16(wh1, bh0v, acc[1][0]);
                acc[1][0] = mfma16(wh1, bl0v, acc[1][0]);
                acc[1][0] = mfma16(wl1, bh0v, acc[1][0]);
                acc[1][1] = mfma16(wh1, bh1v, acc[1][1]);
                acc[1][1] = mfma16(wh1, bl1v, acc[1][1]);
                acc[1][1] = mfma16(wl1, bh1v, acc[1][1]);
                acc[2][0] = mfma16(wh2, bh0v, acc[2][0]);
                acc[2][0] = mfma16(wh2, bl0v, acc[2][0]);
                acc[2][0] = mfma16(wl2, bh0v, acc[2][0]);
                acc[2][1] = mfma16(wh2, bh1v, acc[2][1]);
                acc[2][1] = mfma16(wh2, bl1v, acc[2][1]);
                acc[2][1] = mfma16(wl2, bh1v, acc[2][1]);

                bh0v = nbh0; bh1v = nbh1; bl0v = nbl0; bl1v = nbl1;
                wl0 = nwl0; wl1 = nwl1; wl2 = nwl2;
            }
            // store D: row = RT*48 + s3*16 + q*4 + r4 ; col = (ct0+t)*16 + n
            float* gb = gbuf + (size_t)(L * 2 + HF) * (1536 * 256);
#pragma unroll
            for (int s3 = 0; s3 < 3; ++s3)
#pragma unroll
                for (int t = 0; t < 2; ++t) {
                    const int row0 = RT * 48 + s3 * 16 + q * 4;
                    const int col = (ct0 + t) * 16 + n;
#pragma unroll
                    for (int r4 = 0; r4 < 4; ++r4)
                        gb[(size_t)(row0 + r4) * 256 + col] = acc[s3][t][r4];
                }
        }
        ++phase;
        gbar(bar, phase, grp);

        // ================= PHASE B: elementwise + staging =================
        if (gt < 32768) {
            const int Lj = gt >> 14;
            const int r = gt & 16383;
            const int uo = r >> 8, b = r & 255;
            const bool run = Lj ? (s >= 1) : (s <= TT - 1);
            if (run) {
                const int u0 = uo * 8;
                const float* gi = gbuf + (size_t)(Lj * 2 + 0) * (1536 * 256);
                const float* gh = gbuf + (size_t)(Lj * 2 + 1) * (1536 * 256);
                const float* bi = Lj ? bi1 : bi0;
                const float* bh = Lj ? bh1 : bh0;
                ushort_t hi8[8], lo8[8];
#pragma unroll
                for (int j = 0; j < 8; ++j) {
                    const int u = u0 + j;
                    float gir = gi[(size_t)u * 256 + b] + bi[u];
                    float giz = gi[(size_t)(512 + u) * 256 + b] + bi[512 + u];
                    float gin = gi[(size_t)(1024 + u) * 256 + b] + bi[1024 + u];
                    float ghr = gh[(size_t)u * 256 + b] + bh[u];
                    float ghz = gh[(size_t)(512 + u) * 256 + b] + bh[512 + u];
                    float ghn = gh[(size_t)(1024 + u) * 256 + b] + bh[1024 + u];
                    float rr = sigm(gir + ghr);
                    float zz = sigm(giz + ghz);
                    float nn = tanhf(gin + rr * ghn);
                    float hv = (1.f - zz) * nn + zz * hreg[j];
                    hreg[j] = hv;
                    hi8[j] = f2bf(hv);
                    lo8[j] = f2bf(hv - bf2f(hi8[j]));
                }
                const int t_idx = Lj ? (s - 1) : s;
                ushort_t* pk = (Lj ? h1pack : h0pack) + (size_t)(t_idx & 1) * 2 * PL_USH;
                const int ct = b >> 4, nn2 = b & 15, ch = uo >> 2, qq = uo & 3;
                const size_t o = ((size_t)(ch * 16 + ct) * 64 + qq * 16 + nn2) * 8;
                *(uint4*)(pk + o) = *(uint4*)hi8;
                *(uint4*)(pk + PL_USH + o) = *(uint4*)lo8;
            }
        } else if (gt < 49152) {
            if (s <= TT - 2) {
                const int r = gt - 32768;
                const int ko = r & 63, b = r >> 6;
                const int t = s + 1;
                const float* xs = x + ((size_t)b * TT + t) * NS;
                ushort_t hi8[8], lo8[8];
#pragma unroll
                for (int j = 0; j < 8; ++j) {
                    const int k = ko * 8 + j;
                    float v = (k < NS) ? xs[k] : 0.f;
                    hi8[j] = f2bf(v);
                    lo8[j] = f2bf(v - bf2f(hi8[j]));
                }
                ushort_t* pk = xpack + (size_t)(t & 1) * 2 * PL_USH;
                const int ct = b >> 4, nn2 = b & 15, ch = ko >> 2, qq = ko & 3;
                const size_t o = ((size_t)(ch * 16 + ct) * 64 + qq * 16 + nn2) * 8;
                *(uint4*)(pk + o) = *(uint4*)hi8;
                *(uint4*)(pk + PL_USH + o) = *(uint4*)lo8;
            }
        }
        ++phase;
        gbar(bar, phase, grp);
    }

    // ================= epilogue: FC + silu + softmax + rebalance =================
    {
        const int b = bid;
        float* sh = (float*)smem_raw;       // 512 floats (reuses W LDS region)
        float* scr = sh + 576;
        // reconstruct final h1 (t=249, parity 1) from hi+lo planes
        for (int u = tid; u < HH; u += TBLK) {
            const int uo = u >> 3, j = u & 7;
            const int ct = b >> 4, nn2 = b & 15, ch = uo >> 2, qq = uo & 3;
            const size_t o = ((size_t)(ch * 16 + ct) * 64 + qq * 16 + nn2) * 8 + j;
            const ushort_t* pk = h1pack + (size_t)1 * 2 * PL_USH;
            sh[u] = bf2f(pk[o]) + bf2f(pk[PL_USH + o]);
        }
        __syncthreads();

        const int o1 = tid;
        const bool v2 = (tid + 256) < NS;
        const int o2 = v2 ? (tid + 256) : (NS - 1);
        float a0 = fcb[o1], a1 = fcb[o2];
        const float* f0 = fcw + (size_t)o1 * HH;
        const float* f1 = fcw + (size_t)o2 * HH;
        for (int k = 0; k < HH; ++k) {
            const float hv = sh[k];
            a0 = fmaf(hv, f0[k], a0);
            a1 = fmaf(hv, f1[k], a1);
        }
        float l0 = a0 * sigm(a0);
        float l1 = a1 * sigm(a1);
        float mx = block_max4(fmaxf(l0, v2 ? l1 : -3.4e38f), scr);
        float e0 = expf(l0 - mx);
        float e1 = v2 ? expf(l1 - mx) : 0.f;
        float2 s2 = block_sum2_4(e0 + e1, 0.f, scr);
        float w0 = e0 / s2.x, w1 = e1 / s2.x;
        for (int it = 0; it < 30; ++it) {
            float c0v = fminf(fmaxf(w0, 0.f), 0.1f);
            float c1v = fminf(fmaxf(w1, 0.f), 0.1f);
            float lv = (w0 - c0v) + (w1 - c1v);
            float n0 = (c0v != 0.1f) ? c0v : 0.f;
            float n1 = (v2 && c1v != 0.1f) ? c1v : 0.f;
            float2 rs = block_sum2_4(lv, n0 + n1, scr);
            float inv = rs.x / rs.y;
            w0 = c0v + inv * n0;
            w1 = c1v + inv * n1;
        }
        out[(size_t)b * NS + o1] = w0;
        if (v2) out[(size_t)b * NS + tid + 256] = w1;
    }
}

// ---------------- prep: pack W-lo plane into A-frag order ----------------
__global__ void pack_wlo(const float* __restrict__ wih0, const float* __restrict__ whh0,
                         const float* __restrict__ wih1, const float* __restrict__ whh1,
                         ushort_t* __restrict__ WloP) {
    const int t = blockIdx.x * 256 + threadIdx.x;     // 3,145,728 threads
    const int sl = t / (int)WSLICE_USH;
    const int r = t - sl * (int)WSLICE_USH;
    const int c = r / 1536;
    const int r2 = r - c * 1536;
    const int s3 = r2 >> 9;
    const int p = r2 & 511;
    const int lane = p >> 3, j = p & 7;
    const int m = lane & 15, q = lane >> 4;
    const int L = sl >> 6, HF = (sl >> 5) & 1, RT = sl & 31;
    const int row = RT * 48 + s3 * 16 + m;
    const int k = c * 32 + q * 8 + j;
    const float* W; int K;
    if (L == 0) { W = HF ? whh0 : wih0; K = HF ? HH : NS; }
    else        { W = HF ? whh1 : wih1; K = HH; }
    float v = (k < K) ? W[(size_t)row * K + k] : 0.f;
    ushort_t hi = f2bf(v);
    WloP[t] = f2bf(v - bf2f(hi));
}

// ---------------- prep: pack x[t=0] ----------------
__global__ void pack_x0(const float* __restrict__ x, ushort_t* __restrict__ xpack) {
    const int t = blockIdx.x * 256 + threadIdx.x;   // 16384 threads
    const int ko = t & 63, b = t >> 6;
    const float* xs = x + (size_t)b * TT * NS;      // t=0
    ushort_t hi8[8], lo8[8];
#pragma unroll
    for (int j = 0; j < 8; ++j) {
        const int k = ko * 8 + j;
        float v = (k < NS) ? xs[k] : 0.f;
        hi8[j] = f2bf(v);
        lo8[j] = f2bf(v - bf2f(hi8[j]));
    }
    const int ct = b >> 4, n = b & 15, ch = ko >> 2, q = ko & 3;
    const size_t o = ((size_t)(ch * 16 + ct) * 64 + q * 16 + n) * 8;
    *(uint4*)(xpack + o) = *(uint4*)hi8;
    *(uint4*)(xpack + PL_USH + o) = *(uint4*)lo8;
}

// ---------------- launch ----------------
extern "C" void kernel_launch(void* const* d_in, const int* in_sizes, int n_in,
                              void* d_out, int out_size, void* d_ws, size_t ws_size,
                              hipStream_t stream) {
    const float* x    = (const float*)d_in[0];
    const float* wih0 = (const float*)d_in[1];
    const float* whh0 = (const float*)d_in[2];
    const float* bih0 = (const float*)d_in[3];
    const float* bhh0 = (const float*)d_in[4];
    const float* wih1 = (const float*)d_in[5];
    const float* whh1 = (const float*)d_in[6];
    const float* bih1 = (const float*)d_in[7];
    const float* bhh1 = (const float*)d_in[8];
    const float* fcw  = (const float*)d_in[9];
    const float* fcb  = (const float*)d_in[10];
    float* outp = (float*)d_out;

    // ws layout (total 15,732,736 B < 16 MiB):
    char* ws = (char*)d_ws;
    unsigned* bar    = (unsigned*)ws;                                  // 4 KB
    ushort_t* h0pack = (ushort_t*)(ws + 4096);                         // 1 MB
    ushort_t* h1pack = (ushort_t*)(ws + 4096 + 1048576);               // 1 MB
    ushort_t* xpack  = (ushort_t*)(ws + 4096 + 2097152);               // 1 MB
    ushort_t* WloP   = (ushort_t*)(ws + 4096 + 3145728);               // 6,291,456 B
    float*    gbuf   = (float*)(ws + 4096 + 9437184);                  // 6,291,456 B

    // zero barrier state + h packs (h0 = 0 both parities)
    hipMemsetAsync(ws, 0, 4096 + 2097152, stream);

    pack_wlo<<<12288, 256, 0, stream>>>(wih0, whh0, wih1, whh1, WloP);
    pack_x0<<<64, 256, 0, stream>>>(x, xpack);

    void* args[] = {(void*)&x,
                    (void*)&wih0, (void*)&whh0, (void*)&bih0, (void*)&bhh0,
                    (void*)&wih1, (void*)&whh1, (void*)&bih1, (void*)&bhh1,
                    (void*)&fcw, (void*)&fcb, (void*)&WloP,
                    (void*)&xpack, (void*)&h0pack, (void*)&h1pack,
                    (void*)&gbuf, (void*)&bar, (void*)&outp};
    hipError_t e = hipLaunchCooperativeKernel((const void*)gru_main, dim3(NBLK), dim3(TBLK),
                                              args, 49408, stream);
    if (e != hipSuccess) {
        gru_main<<<dim3(NBLK), dim3(TBLK), 49408, stream>>>(
            x, wih0, whh0, bih0, bhh0, wih1, whh1, bih1, bhh1,
            fcw, fcb, WloP, xpack, h0pack, h1pack, gbuf, bar, outp);
    }
}

// Round 5
// 21164.247 us; speedup vs baseline: 4.6675x; 1.6046x over previous
//
#include <hip/hip_runtime.h>
#include <math.h>

typedef __attribute__((ext_vector_type(8))) short short8;
typedef __attribute__((ext_vector_type(4))) float floatx4;
typedef unsigned short ushort_t;
typedef unsigned int uint32;

#define BB 256
#define TT 250
#define NS 500
#define HH 512
#define TNS (TT * NS)
#define NBLK 256
#define TBLK 256
#define PL_USH 131072u      // act plane: 16ch*16ct*64lane*8 ushorts (512K x 256 bf16)
#define CH_USH 8192u        // act chunk stride: 16ct*64*8
// LDS: whi 64KB + wlo 64KB + scratch 2*32*65 floats
#define WHI_USH 32768
#define SCR_OFF 131072
#define SMEMB (131072 + 2 * 32 * 65 * 4)   // 147712 B

// ---- bf16 split helpers (RNE) ----
__device__ __forceinline__ ushort_t f2bf(float f) {
    uint32 u = __float_as_uint(f);
    u += 0x7fffu + ((u >> 16) & 1u);
    return (ushort_t)(u >> 16);
}
__device__ __forceinline__ float bf2f(ushort_t h) { return __uint_as_float(((uint32)h) << 16); }
__device__ __forceinline__ float sigm(float x) { return 1.f / (1.f + expf(-x)); }
__device__ __forceinline__ floatx4 mfma16(short8 a, short8 b, floatx4 c) {
    return __builtin_amdgcn_mfma_f32_16x16x32_bf16(a, b, c, 0, 0, 0);
}

// ------------- radix-4 dissemination barrier: 4 rounds, 3 partners/round -------------
// flags: 4*3*256 slots, each padded to 64B (16 uints). Single writer/reader per slot.
__device__ __forceinline__ void dbar(unsigned* flags, unsigned phase, int bid) {
    __threadfence();
    __syncthreads();
    const int tj = threadIdx.x;
#pragma unroll
    for (int r = 0; r < 4; ++r) {
        if (tj < 3) {
            const int j = tj + 1;
            const int d = j << (2 * r);
            unsigned* dst = flags + ((size_t)((r * 3 + tj) * 256 + bid) << 4);
            __hip_atomic_store(dst, phase, __ATOMIC_RELEASE, __HIP_MEMORY_SCOPE_AGENT);
            unsigned* src = flags + ((size_t)((r * 3 + tj) * 256 + ((bid - d) & 255)) << 4);
            while (__hip_atomic_load(src, __ATOMIC_ACQUIRE, __HIP_MEMORY_SCOPE_AGENT) < phase)
                __builtin_amdgcn_s_sleep(1);
        }
        __syncthreads();
    }
}

// ---------------- block reductions (256 thr = 4 waves) ----------------
__device__ __forceinline__ float block_max4(float v, float* scr) {
#pragma unroll
    for (int off = 32; off; off >>= 1) v = fmaxf(v, __shfl_down(v, off, 64));
    if ((threadIdx.x & 63) == 0) scr[threadIdx.x >> 6] = v;
    __syncthreads();
    if (threadIdx.x == 0)
        scr[8] = fmaxf(fmaxf(scr[0], scr[1]), fmaxf(scr[2], scr[3]));
    __syncthreads();
    float r = scr[8];
    __syncthreads();
    return r;
}
__device__ __forceinline__ float2 block_sum2_4(float a, float b, float* scr) {
#pragma unroll
    for (int off = 32; off; off >>= 1) {
        a += __shfl_down(a, off, 64);
        b += __shfl_down(b, off, 64);
    }
    if ((threadIdx.x & 63) == 0) { int w = threadIdx.x >> 6; scr[w] = a; scr[4 + w] = b; }
    __syncthreads();
    if (threadIdx.x == 0) {
        scr[8] = scr[0] + scr[1] + scr[2] + scr[3];
        scr[9] = scr[4] + scr[5] + scr[6] + scr[7];
    }
    __syncthreads();
    float2 r = make_float2(scr[8], scr[9]);
    __syncthreads();
    return r;
}

// ------------- one K-half GEMM (16 chunks of K=32), depth-3 B prefetch ring -------------
// ap: act B-frag base (pre-offset to this wave's first col-tile, hi plane; lo at +PL_USH)
// whiS/wloS: LDS W frag bases (pre-offset by lane*8); c0 = 0 (gi) or 16 (gh)
__device__ __forceinline__ void gemm_half(const ushort_t* __restrict__ ap,
                                          const ushort_t* whiS, const ushort_t* wloS,
                                          int c0, floatx4 (&acc)[2][2]) {
    short8 Bh0[4], Bh1[4], Bl0[4], Bl1[4];
#pragma unroll
    for (int pc = 0; pc < 3; ++pc) {
        const ushort_t* p = ap + (size_t)pc * CH_USH;
        Bh0[pc] = *(const short8*)(p);
        Bh1[pc] = *(const short8*)(p + 512);
        Bl0[pc] = *(const short8*)(p + PL_USH);
        Bl1[pc] = *(const short8*)(p + PL_USH + 512);
    }
#pragma unroll
    for (int c = 0; c < 16; ++c) {
        if (c < 13) {
            const int pc = c + 3;
            const ushort_t* p = ap + (size_t)pc * CH_USH;
            Bh0[pc & 3] = *(const short8*)(p);
            Bh1[pc & 3] = *(const short8*)(p + 512);
            Bl0[pc & 3] = *(const short8*)(p + PL_USH);
            Bl1[pc & 3] = *(const short8*)(p + PL_USH + 512);
        }
        const int wc = (c0 + c) * 2;
        short8 w0h = *(const short8*)(whiS + (size_t)wc * 512);
        short8 w1h = *(const short8*)(whiS + (size_t)(wc + 1) * 512);
        short8 w0l = *(const short8*)(wloS + (size_t)wc * 512);
        short8 w1l = *(const short8*)(wloS + (size_t)(wc + 1) * 512);
        const int cs = c & 3;
        acc[0][0] = mfma16(w0h, Bh0[cs], acc[0][0]);
        acc[0][0] = mfma16(w0h, Bl0[cs], acc[0][0]);
        acc[0][0] = mfma16(w0l, Bh0[cs], acc[0][0]);
        acc[0][1] = mfma16(w0h, Bh1[cs], acc[0][1]);
        acc[0][1] = mfma16(w0h, Bl1[cs], acc[0][1]);
        acc[0][1] = mfma16(w0l, Bh1[cs], acc[0][1]);
        acc[1][0] = mfma16(w1h, Bh0[cs], acc[1][0]);
        acc[1][0] = mfma16(w1h, Bl0[cs], acc[1][0]);
        acc[1][0] = mfma16(w1l, Bh0[cs], acc[1][0]);
        acc[1][1] = mfma16(w1h, Bh1[cs], acc[1][1]);
        acc[1][1] = mfma16(w1h, Bl1[cs], acc[1][1]);
        acc[1][1] = mfma16(w1l, Bh1[cs], acc[1][1]);
    }
}

// ---------------- main persistent kernel ----------------
// 256 blocks = L(2) x UG(64 groups of 8 units) x CT(2 col-halves of 128).
// Each block: full GRU cell for its 8 units x 128 batches per step. One barrier/step.
__global__ void __launch_bounds__(TBLK, 1)
gru_main(const float* __restrict__ x,
         const float* __restrict__ wih0, const float* __restrict__ whh0,
         const float* __restrict__ bi0,  const float* __restrict__ bh0,
         const float* __restrict__ wih1, const float* __restrict__ whh1,
         const float* __restrict__ bi1,  const float* __restrict__ bh1,
         const float* __restrict__ fcb,  const float* __restrict__ fcT,
         ushort_t* xpack, ushort_t* h0pack, ushort_t* h1pack,
         unsigned* flags,
         float* __restrict__ out)
{
    extern __shared__ char smem_raw[];
    ushort_t* whi = (ushort_t*)smem_raw;            // 32768 ush (64 KB)
    ushort_t* wlo = whi + WHI_USH;                  // 64 KB
    float* scrF = (float*)(smem_raw + SCR_OFF);     // [2][32][65] floats

    const int bid = blockIdx.x, tid = threadIdx.x;
    const int L  = bid >> 7;
    const int UG = (bid >> 1) & 63;      // 8-unit group
    const int CT = bid & 1;              // col half (128 batches)
    const int wid = tid >> 6, lane = tid & 63;
    const int q = lane >> 4, n = lane & 15;

    // ---- stage this block's weights into LDS (hi+lo planes, A-frag layout) ----
    {
        const float* Wgi = L ? wih1 : wih0;
        const float* Wgh = L ? whh1 : whh0;
        const int Kgi = L ? HH : NS;
        for (int idx = tid; idx < 32768; idx += TBLK) {
            const int j = idx & 7, ln = (idx >> 3) & 63, rc = idx >> 9;  // rc = wc*2+rt
            const int c = rc >> 1, rt = rc & 1;
            const int m = ln & 15, qq = ln >> 4;
            const int lr = rt * 16 + m;          // 0..31 (rows 24..31 pad)
            const int g = lr >> 3, u = lr & 7;
            float v = 0.f;
            if (g < 3) {
                if (c < 16) {
                    const int k = c * 32 + qq * 8 + j;
                    if (k < Kgi) v = Wgi[(size_t)(g * HH + UG * 8 + u) * Kgi + k];
                } else {
                    const int k = (c - 16) * 32 + qq * 8 + j;
                    v = Wgh[(size_t)(g * HH + UG * 8 + u) * HH + k];
                }
            }
            const ushort_t hb = f2bf(v);
            whi[idx] = hb;
            wlo[idx] = f2bf(v - bf2f(hb));
        }
    }

    // per-thread elementwise assignment: units u2,u2+1; cols h*64 + lb (h=round)
    const int lb = tid & 63, u2 = (tid >> 6) * 2;
    float biR[2], biZ[2], biN[2], bhR[2], bhZ[2], bhN[2];
    {
        const float* bi = L ? bi1 : bi0;
        const float* bh = L ? bh1 : bh0;
#pragma unroll
        for (int p = 0; p < 2; ++p) {
            const int ugl = UG * 8 + u2 + p;
            biR[p] = bi[ugl]; biZ[p] = bi[HH + ugl]; biN[p] = bi[2 * HH + ugl];
            bhR[p] = bh[ugl]; bhZ[p] = bh[HH + ugl]; bhN[p] = bh[2 * HH + ugl];
        }
    }
    float hreg[4] = {0.f, 0.f, 0.f, 0.f};   // [round h][p]
    const int chW = UG >> 2, qqW = UG & 3;  // pack-write constants
    __syncthreads();

    const ushort_t* whiS = whi + (size_t)lane * 8;
    const ushort_t* wloS = wlo + (size_t)lane * 8;
    const size_t apoff = ((size_t)(CT * 8 + wid * 2) * 64 + lane) * 8;

    unsigned phase = 0;
    for (int s = 0; s <= TT; ++s) {
        const bool active = L ? (s >= 1) : (s < TT);
        if (active) {
            const ushort_t *gisrc, *ghsrc;
            if (L == 0) {
                gisrc = xpack + (size_t)(s & 1) * 2 * PL_USH;
                ghsrc = h0pack + (size_t)((s - 1) & 1) * 2 * PL_USH;
            } else {
                gisrc = h0pack + (size_t)((s - 1) & 1) * 2 * PL_USH;
                ghsrc = h1pack + (size_t)(s & 1) * 2 * PL_USH;
            }
            floatx4 z4 = {0.f, 0.f, 0.f, 0.f};
            floatx4 aGI[2][2], aGH[2][2];
#pragma unroll
            for (int i = 0; i < 2; ++i) { aGI[i][0] = z4; aGI[i][1] = z4; aGH[i][0] = z4; aGH[i][1] = z4; }
            gemm_half(gisrc + apoff, whiS, wloS, 0,  aGI);
            gemm_half(ghsrc + apoff, whiS, wloS, 16, aGH);

            // ---- x staging loads for step s+1 (issue early, store later) ----
            float4 xv0, xv1;
            const bool doX = (s <= TT - 2) && (bid * TBLK + tid < 16384);
            int xko = 0, xb = 0;
            if (doX) {
                const int gx = bid * TBLK + tid;
                xko = gx & 63; xb = gx >> 6;
                const float* xs = x + ((size_t)xb * TT + (s + 1)) * NS + xko * 8;
                if (xko < 62) { xv0 = *(const float4*)(xs); xv1 = *(const float4*)(xs + 4); }
                else {  // ko 62: k 496..499 valid; ko 63: none
                    float tmp[8];
#pragma unroll
                    for (int j = 0; j < 8; ++j) {
                        const int k = xko * 8 + j;
                        tmp[j] = (k < NS) ? xs[j] : 0.f;
                    }
                    xv0 = make_float4(tmp[0], tmp[1], tmp[2], tmp[3]);
                    xv1 = make_float4(tmp[4], tmp[5], tmp[6], tmp[7]);
                }
            }

            // ---- elementwise in two col-rounds through LDS scratch ----
            ushort_t* pk = L ? h1pack + (size_t)((s - 1) & 1) * 2 * PL_USH
                             : h0pack + (size_t)(s & 1) * 2 * PL_USH;
#pragma unroll
            for (int h = 0; h < 2; ++h) {
                if ((wid >> 1) == h) {
#pragma unroll
                    for (int rt = 0; rt < 2; ++rt)
#pragma unroll
                        for (int t = 0; t < 2; ++t) {
                            const int row0 = rt * 16 + q * 4;
                            const int colr = ((wid & 1) * 2 + t) * 16 + n;
#pragma unroll
                            for (int r4 = 0; r4 < 4; ++r4) {
                                scrF[(row0 + r4) * 65 + colr] = aGI[rt][t][r4];
                                scrF[2080 + (row0 + r4) * 65 + colr] = aGH[rt][t][r4];
                            }
                        }
                }
                __syncthreads();
#pragma unroll
                for (int p = 0; p < 2; ++p) {
                    const int u = u2 + p;
                    const float gir = scrF[u * 65 + lb],        ghr = scrF[2080 + u * 65 + lb];
                    const float giz = scrF[(8 + u) * 65 + lb],  ghz = scrF[2080 + (8 + u) * 65 + lb];
                    const float gin = scrF[(16 + u) * 65 + lb], ghn = scrF[2080 + (16 + u) * 65 + lb];
                    const float rr = sigm(gir + biR[p] + ghr + bhR[p]);
                    const float zz = sigm(giz + biZ[p] + ghz + bhZ[p]);
                    const float nn = tanhf(gin + biN[p] + rr * (ghn + bhN[p]));
                    const float hv = (1.f - zz) * nn + zz * hreg[h * 2 + p];
                    hreg[h * 2 + p] = hv;
                    const int b = CT * 128 + h * 64 + lb;
                    const size_t o = ((size_t)(chW * 16 + (b >> 4)) * 64 + qqW * 16 + (b & 15)) * 8 + u;
                    const ushort_t hb = f2bf(hv);
                    pk[o] = hb;
                    pk[PL_USH + o] = f2bf(hv - bf2f(hb));
                }
                __syncthreads();
            }

            // ---- x staging stores ----
            if (doX) {
                ushort_t hi8[8], lo8[8];
                float vv[8] = {xv0.x, xv0.y, xv0.z, xv0.w, xv1.x, xv1.y, xv1.z, xv1.w};
#pragma unroll
                for (int j = 0; j < 8; ++j) {
                    hi8[j] = f2bf(vv[j]);
                    lo8[j] = f2bf(vv[j] - bf2f(hi8[j]));
                }
                ushort_t* xp = xpack + (size_t)((s + 1) & 1) * 2 * PL_USH;
                const size_t o = ((size_t)((xko >> 2) * 16 + (xb >> 4)) * 64 + (xko & 3) * 16 + (xb & 15)) * 8;
                *(uint4*)(xp + o) = *(uint4*)hi8;
                *(uint4*)(xp + PL_USH + o) = *(uint4*)lo8;
            }
        } else if ((s <= TT - 2) && (bid * TBLK + tid < 16384)) {
            // inactive blocks still stage x
            const int gx = bid * TBLK + tid;
            const int xko = gx & 63, xb = gx >> 6;
            const float* xs = x + ((size_t)xb * TT + (s + 1)) * NS + xko * 8;
            ushort_t hi8[8], lo8[8];
#pragma unroll
            for (int j = 0; j < 8; ++j) {
                const int k = xko * 8 + j;
                const float v = (k < NS) ? xs[j] : 0.f;
                hi8[j] = f2bf(v);
                lo8[j] = f2bf(v - bf2f(hi8[j]));
            }
            ushort_t* xp = xpack + (size_t)((s + 1) & 1) * 2 * PL_USH;
            const size_t o = ((size_t)((xko >> 2) * 16 + (xb >> 4)) * 64 + (xko & 3) * 16 + (xb & 15)) * 8;
            *(uint4*)(xp + o) = *(uint4*)hi8;
            *(uint4*)(xp + PL_USH + o) = *(uint4*)lo8;
        }
        ++phase;
        dbar(flags, phase, bid);
    }

    // ================= epilogue: FC + silu + softmax + rebalance (block = batch) =========
    {
        const int b = bid;
        float* sh = (float*)smem_raw;       // 512 floats
        float* scr = sh + 576;
        const ushort_t* pk = h1pack + (size_t)1 * 2 * PL_USH;   // h1[249], parity 1
        for (int u = tid; u < HH; u += TBLK) {
            const int uo = u >> 3, j = u & 7;
            const size_t o = ((size_t)((uo >> 2) * 16 + (b >> 4)) * 64 + (uo & 3) * 16 + (b & 15)) * 8 + j;
            sh[u] = bf2f(pk[o]) + bf2f(pk[PL_USH + o]);
        }
        __syncthreads();

        const int o1 = tid;
        const bool v2 = (tid + 256) < NS;
        const int o2 = v2 ? (tid + 256) : (NS - 1);
        float a0 = fcb[o1], a1 = fcb[o2];
        for (int k = 0; k < HH; ++k) {
            const float hv = sh[k];
            const float* fr = fcT + (size_t)k * NS;
            a0 = fmaf(hv, fr[o1], a0);
            a1 = fmaf(hv, fr[o2], a1);
        }
        float l0 = a0 * sigm(a0);
        float l1 = a1 * sigm(a1);
        float mx = block_max4(fmaxf(l0, v2 ? l1 : -3.4e38f), scr);
        float e0 = expf(l0 - mx);
        float e1 = v2 ? expf(l1 - mx) : 0.f;
        float2 s2 = block_sum2_4(e0 + e1, 0.f, scr);
        float w0 = e0 / s2.x, w1 = e1 / s2.x;
        for (int it = 0; it < 30; ++it) {
            float c0v = fminf(fmaxf(w0, 0.f), 0.1f);
            float c1v = fminf(fmaxf(w1, 0.f), 0.1f);
            float lv = (w0 - c0v) + (w1 - c1v);
            float n0 = (c0v != 0.1f) ? c0v : 0.f;
            float n1 = (v2 && c1v != 0.1f) ? c1v : 0.f;
            float2 rs = block_sum2_4(lv, n0 + n1, scr);
            float inv = rs.x / rs.y;
            w0 = c0v + inv * n0;
            w1 = c1v + inv * n1;
        }
        out[(size_t)b * NS + o1] = w0;
        if (v2) out[(size_t)b * NS + tid + 256] = w1;
    }
}

// ---------------- prep: pack x[t=0] ----------------
__global__ void pack_x0(const float* __restrict__ x, ushort_t* __restrict__ xpack) {
    const int t = blockIdx.x * 256 + threadIdx.x;   // 16384 threads
    const int ko = t & 63, b = t >> 6;
    const float* xs = x + (size_t)b * TT * NS;      // t=0
    ushort_t hi8[8], lo8[8];
#pragma unroll
    for (int j = 0; j < 8; ++j) {
        const int k = ko * 8 + j;
        const float v = (k < NS) ? xs[k] : 0.f;
        hi8[j] = f2bf(v);
        lo8[j] = f2bf(v - bf2f(hi8[j]));
    }
    const size_t o = ((size_t)((ko >> 2) * 16 + (b >> 4)) * 64 + (ko & 3) * 16 + (b & 15)) * 8;
    *(uint4*)(xpack + o) = *(uint4*)hi8;
    *(uint4*)(xpack + PL_USH + o) = *(uint4*)lo8;
}

// ---------------- prep: fc weight transpose ----------------
__global__ void transpose_k(const float* __restrict__ src, float* __restrict__ dst,
                            int G, int K) {
    int idx = blockIdx.x * 256 + threadIdx.x;
    if (idx >= G * K) return;
    int k = idx / G, g = idx - k * G;
    dst[idx] = src[(size_t)g * K + k];
}

// ---------------- launch ----------------
extern "C" void kernel_launch(void* const* d_in, const int* in_sizes, int n_in,
                              void* d_out, int out_size, void* d_ws, size_t ws_size,
                              hipStream_t stream) {
    const float* x    = (const float*)d_in[0];
    const float* wih0 = (const float*)d_in[1];
    const float* whh0 = (const float*)d_in[2];
    const float* bih0 = (const float*)d_in[3];
    const float* bhh0 = (const float*)d_in[4];
    const float* wih1 = (const float*)d_in[5];
    const float* whh1 = (const float*)d_in[6];
    const float* bih1 = (const float*)d_in[7];
    const float* bhh1 = (const float*)d_in[8];
    const float* fcw  = (const float*)d_in[9];
    const float* fcb  = (const float*)d_in[10];
    float* outp = (float*)d_out;

    // ws layout (~4.4 MB):
    char* ws = (char*)d_ws;
    unsigned* flags  = (unsigned*)ws;                         // 4*3*256*64B = 196608
    ushort_t* h0pack = (ushort_t*)(ws + 196608);              // 1 MB
    ushort_t* h1pack = (ushort_t*)(ws + 196608 + 1048576);    // 1 MB
    ushort_t* xpack  = (ushort_t*)(ws + 196608 + 2097152);    // 1 MB
    float*    fcT    = (float*)(ws + 196608 + 3145728);       // 512*500*4 = 1024000

    // zero: flags + h packs (h0 = 0 both parities)
    hipMemsetAsync(ws, 0, 196608 + 2097152, stream);
    pack_x0<<<64, 256, 0, stream>>>(x, xpack);
    {
        int nel = NS * HH;
        transpose_k<<<(nel + 255) / 256, 256, 0, stream>>>(fcw, fcT, NS, HH);
    }

    hipFuncSetAttribute((const void*)gru_main,
                        hipFuncAttributeMaxDynamicSharedMemorySize, SMEMB);

    void* args[] = {(void*)&x,
                    (void*)&wih0, (void*)&whh0, (void*)&bih0, (void*)&bhh0,
                    (void*)&wih1, (void*)&whh1, (void*)&bih1, (void*)&bhh1,
                    (void*)&fcb, (void*)&fcT,
                    (void*)&xpack, (void*)&h0pack, (void*)&h1pack,
                    (void*)&flags, (void*)&outp};
    hipError_t e = hipLaunchCooperativeKernel((const void*)gru_main, dim3(NBLK), dim3(TBLK),
                                              args, SMEMB, stream);
    if (e != hipSuccess) {
        gru_main<<<dim3(NBLK), dim3(TBLK), SMEMB, stream>>>(
            x, wih0, whh0, bih0, bhh0, wih1, whh1, bih1, bhh1,
            fcb, fcT, xpack, h0pack, h1pack, flags, outp);
    }
}